// Round 11
// baseline (221.416 us; speedup 1.0000x reference)
//
#include <hip/hip_runtime.h>
#include <hip/hip_bf16.h>

#define NUM_GRAPHS 64
#define NODES 256
#define EDGES 1024
#define NTOT (NUM_GRAPHS * NODES) /* 16384 */
#define DF 512
#define HF 1024
#define HP 256
#define NC 10
#define INF32 0xFFFFFFFFu

typedef short bf16x8 __attribute__((ext_vector_type(8)));
typedef float f32x4 __attribute__((ext_vector_type(4)));

__device__ __forceinline__ unsigned short bf16r(float f) {
    __hip_bfloat16 h = __float2bfloat16(f);
    return *(unsigned short*)&h;
}
// monotone order-preserving encode for fp32 (bijection, works for +/-)
__device__ __forceinline__ unsigned encf(float x) {
    union { float f; unsigned u; } c; c.f = x;
    return (c.u & 0x80000000u) ? ~c.u : (c.u | 0x80000000u);
}

// ---- w1 (f32 [k][j]) -> w1f bf16, LANE-ORDERED MFMA B-fragment layout ----
// Element addr: ((cg*16 + t)*64 + lane)*8 shorts, lane = quad*16 + n16;
// lane holds B[k = t*32 + quad*8 + j][col = cg*16 + n16].
__global__ __launch_bounds__(256) void k_cvt_frag(
    const float* __restrict__ w1, unsigned short* __restrict__ w1f)
{
    __shared__ float ls[128 * 16];   // [kk][c], 8 KB
    const int tid = threadIdx.x;
    const int cg = blockIdx.x >> 2, kq = blockIdx.x & 3;
    const int c = tid & 15, kr = tid >> 4;
#pragma unroll
    for (int it = 0; it < 8; ++it) {
        int kk = it * 16 + kr;
        ls[kk * 16 + c] = w1[(size_t)(kq * 128 + kk) * HF + cg * 16 + c];
    }
    __syncthreads();
    const int tt = tid >> 6, n16 = tid & 15, q = (tid >> 4) & 3;
    unsigned short v[8];
#pragma unroll
    for (int j = 0; j < 8; ++j)
        v[j] = bf16r(ls[(tt * 32 + q * 8 + j) * 16 + n16]);
    size_t off = ((size_t)(cg * 16 + kq * 4 + tt) * 64 + (q * 16 + n16)) * 8;
#pragma unroll
    for (int j = 0; j < 8; ++j) w1f[off + j] = v[j];
}

// ------- Stage 1 (MFMA v6): zbuf = relu(x@W1+b1)@w2 (pre-b2/sigmoid) ------
// Reverted to the R9-proven reg-staged version (v14 gl_lds was neutral).
__global__ __launch_bounds__(256, 1) void k_fil_mfma(
    const float* __restrict__ x, const unsigned short* __restrict__ w1f,
    const float* __restrict__ b1, const float* __restrict__ w2,
    float* __restrict__ zbuf)
{
    __shared__ unsigned short Bbuf[4 * 16 * 512];  // 4 x 16 KB
    __shared__ float zpart[4][32];
    const int tid = threadIdx.x;
    const int lane = tid & 63;
    const int wv = tid >> 6;            // 0..3
    const int l15 = lane & 15, quad = lane >> 4;
    const int half = wv >> 1;           // column half (32 cgs)
    const int rt = wv & 1;              // row 32-tile
    const int r0 = blockIdx.x * 64;
    const int rowA = r0 + rt * 32 + l15;
    const int rowB = rowA + 16;

    // A fragments for 32 rows: two 16-row tiles, f32 -> bf16 in regs
    bf16x8 A0[16], A1[16];
#pragma unroll
    for (int t = 0; t < 16; ++t) {
        const float* s0 = x + (size_t)rowA * DF + t * 32 + quad * 8;
        const float* s1 = x + (size_t)rowB * DF + t * 32 + quad * 8;
        float4 a = *(const float4*)s0, b = *(const float4*)(s0 + 4);
        float4 c = *(const float4*)s1, d = *(const float4*)(s1 + 4);
        A0[t][0]=(short)bf16r(a.x); A0[t][1]=(short)bf16r(a.y);
        A0[t][2]=(short)bf16r(a.z); A0[t][3]=(short)bf16r(a.w);
        A0[t][4]=(short)bf16r(b.x); A0[t][5]=(short)bf16r(b.y);
        A0[t][6]=(short)bf16r(b.z); A0[t][7]=(short)bf16r(b.w);
        A1[t][0]=(short)bf16r(c.x); A1[t][1]=(short)bf16r(c.y);
        A1[t][2]=(short)bf16r(c.z); A1[t][3]=(short)bf16r(c.w);
        A1[t][4]=(short)bf16r(d.x); A1[t][5]=(short)bf16r(d.y);
        A1[t][6]=(short)bf16r(d.z); A1[t][7]=(short)bf16r(d.w);
    }

    // staging: threads 0-127 stage half 0, 128-255 stage half 1 (8 uint4 ea)
    const int t128 = tid & 127;
    const int sh = tid >> 7;
    uint4 pf[8];
    {
        const uint4* s = (const uint4*)(w1f + (size_t)(sh * 32) * 8192);
#pragma unroll
        for (int j = 0; j < 8; ++j) pf[j] = s[t128 + j * 128];
        uint4* d = (uint4*)Bbuf + (sh * 2 + 0) * 1024;
#pragma unroll
        for (int j = 0; j < 8; ++j) d[t128 + j * 128] = pf[j];
    }
    __syncthreads();

    float s_[2][4] = {{0,0,0,0},{0,0,0,0}};

    for (int i = 0; i < 32; ++i) {
        const int par = i & 1;
        if (i < 31) {
            const uint4* s = (const uint4*)(w1f + (size_t)(sh * 32 + i + 1) * 8192);
#pragma unroll
            for (int j = 0; j < 8; ++j) pf[j] = s[t128 + j * 128];
        }
        const unsigned short* bb = Bbuf + (half * 2 + par) * 8192 + lane * 8;
        f32x4 a00={0,0,0,0}, a01={0,0,0,0}, a10={0,0,0,0}, a11={0,0,0,0};
#pragma unroll
        for (int t = 0; t < 8; ++t) {
            bf16x8 Bf0 = *(const bf16x8*)(bb + t * 512);
            bf16x8 Bf1 = *(const bf16x8*)(bb + (t + 8) * 512);
            a00 = __builtin_amdgcn_mfma_f32_16x16x32_bf16(A0[t], Bf0, a00, 0, 0, 0);
            a10 = __builtin_amdgcn_mfma_f32_16x16x32_bf16(A1[t], Bf0, a10, 0, 0, 0);
            a01 = __builtin_amdgcn_mfma_f32_16x16x32_bf16(A0[t + 8], Bf1, a01, 0, 0, 0);
            a11 = __builtin_amdgcn_mfma_f32_16x16x32_bf16(A1[t + 8], Bf1, a11, 0, 0, 0);
        }
        const int col = (half * 32 + i) * 16 + l15;
        const float b1c = b1[col], w2c = w2[col];
#pragma unroll
        for (int r = 0; r < 4; ++r) {
            float h0 = (a00[r] + a01[r]) + b1c; h0 = h0 > 0.f ? h0 : 0.f;
            s_[0][r] = fmaf(h0, w2c, s_[0][r]);
            float h1 = (a10[r] + a11[r]) + b1c; h1 = h1 > 0.f ? h1 : 0.f;
            s_[1][r] = fmaf(h1, w2c, s_[1][r]);
        }
        if (i < 31) {
            uint4* d = (uint4*)Bbuf + (sh * 2 + (par ^ 1)) * 1024;
#pragma unroll
            for (int j = 0; j < 8; ++j) d[t128 + j * 128] = pf[j];
        }
        __syncthreads();
    }

    // reduce over 16 col-lanes; publish per-wave partials; join halves
#pragma unroll
    for (int sub = 0; sub < 2; ++sub)
#pragma unroll
        for (int r = 0; r < 4; ++r) {
            float v = s_[sub][r];
            v += __shfl_xor(v, 1, 16);
            v += __shfl_xor(v, 2, 16);
            v += __shfl_xor(v, 4, 16);
            v += __shfl_xor(v, 8, 16);
            if (l15 == 0) zpart[wv][sub * 16 + quad * 4 + r] = v;
        }
    __syncthreads();
    if (tid < 64) {
        int rrt = tid >> 5, idx = tid & 31;
        zbuf[r0 + tid] = zpart[rrt][idx] + zpart[rrt + 2][idx];
    }
}

// ---------------- Stage 1 legacy (fp32 VALU) — ws_size fallback -----------
#define TN2 16
__global__ __launch_bounds__(256) void k_fil(
    const float* __restrict__ x, const float* __restrict__ w1,
    const float* __restrict__ b1, const float* __restrict__ w2,
    float* __restrict__ zout)
{
    __shared__ float xs[TN2][DF];
    __shared__ float part[256];
    const int tid = threadIdx.x;
    const int n0 = blockIdx.x * TN2;
    for (int c = tid; c < TN2 * DF / 4; c += 256) {
        int n = c >> 7, k4 = (c & 127) << 2;
        *(float4*)&xs[n][k4] = *(const float4*)(x + (size_t)(n0 + n) * DF + k4);
    }
    __syncthreads();
    float h[TN2][4];
#pragma unroll
    for (int n = 0; n < TN2; ++n)
#pragma unroll
        for (int q = 0; q < 4; ++q) h[n][q] = 0.f;
    for (int k = 0; k < DF; ++k) {
        float wr[4];
#pragma unroll
        for (int q = 0; q < 4; ++q) wr[q] = w1[(size_t)k * HF + tid + 256 * q];
#pragma unroll
        for (int n = 0; n < TN2; ++n) {
            float xv = xs[n][k];
#pragma unroll
            for (int q = 0; q < 4; ++q) h[n][q] = fmaf(xv, wr[q], h[n][q]);
        }
    }
    float b1r[4], w2r[4];
#pragma unroll
    for (int q = 0; q < 4; ++q) { b1r[q] = b1[tid + 256 * q]; w2r[q] = w2[tid + 256 * q]; }
    for (int n = 0; n < TN2; ++n) {
        float s = 0.f;
#pragma unroll
        for (int q = 0; q < 4; ++q) {
            float hv = h[n][q] + b1r[q];
            s += (hv > 0.f ? hv : 0.f) * w2r[q];
        }
        part[tid] = s;
        __syncthreads();
        for (int off = 128; off > 0; off >>= 1) {
            if (tid < off) part[tid] += part[tid + off];
            __syncthreads();
        }
        if (tid == 0) zout[n0 + n] = part[0];
        __syncthreads();
    }
}

// --- Stage 2+3 (v15): FUSED per-graph persistence (both signs) + head -----
// One 512-thread block per graph: half hs=tid>>8 runs the proven v7 Boruvka+
// replay pipeline for sign hs on its own LDS arrays ([hs] indexed). Shared
// `chg` ORs both halves (extra rounds for a finished half are no-ops); the
// jumping loop's __syncthreads_and requires both halves converged. The two
// serial replays run CONCURRENTLY on wave 0 (hs=0) and wave 4 (hs=1).
// Death values land in LDS (original vertex order); phi-MLP + pooling +
// head computed inline (node loop split across halves). Kills the k_head
// launch + the dbuf global round-trip.
__global__ __launch_bounds__(512) void k_pers_head(
    const int* __restrict__ edges, const float* __restrict__ zbuf,
    const float* __restrict__ b2,
    const float* __restrict__ wp0, const float* __restrict__ bp0,
    const float* __restrict__ wp1, const float* __restrict__ bp1,
    const float* __restrict__ wh, const float* __restrict__ bh,
    float* __restrict__ out)
{
    const int g = blockIdx.x;
    const int tid = threadIdx.x;        // 0..511
    const int hs = tid >> 8;            // sign half: 0 -> +f, 1 -> -f
    const int t = tid & 255;

    __shared__ float fv[2][NODES];
    __shared__ unsigned long long vkey[2][NODES];
    __shared__ int order_[2][NODES], rank_[2][NODES];
    __shared__ float fvr[2][NODES];
    __shared__ unsigned eks[2][EDGES];
    __shared__ int comp[2][NODES];
    __shared__ unsigned minE[2][NODES];
    __shared__ int nxt[2][NODES], par2[2][NODES];
    __shared__ unsigned char mstflag[2][EDGES];
    __shared__ int cnt[2];
    __shared__ int chg;
    __shared__ unsigned mstK[2][NODES], srt[2][NODES];
    __shared__ int par[2][NODES], dr[2][NODES], cmaxr[2][NODES];
    __shared__ float dsv[2][NODES];     // deaths, ORIGINAL vertex order
    __shared__ float sred0[512], sred1[512];
    __shared__ float wpart[4][NC];

    float z0 = zbuf[g * NODES + t];
    float f0 = 1.f / (1.f + expf(-(z0 + b2[0])));
    float fvt = hs ? -f0 : f0;
    fv[hs][t] = fvt;
    unsigned long long myk = ((unsigned long long)encf(fvt) << 32) | (unsigned)t;
    vkey[hs][t] = myk;
    srt[hs][t] = INF32; dr[hs][t] = -1; cmaxr[hs][t] = 0; par[hs][t] = t;
    comp[hs][t] = t;
    __syncthreads();

    // counting rank (keys unique): rank = #{j : key[j] < mine}
    {
        int rk = 0;
#pragma unroll 8
        for (int j = 0; j < NODES; ++j) rk += (vkey[hs][j] < myk) ? 1 : 0;
        order_[hs][rk] = t;
        rank_[hs][t] = rk;
        fvr[hs][rk] = fvt;
    }
    __syncthreads();

    // edge keys in rank domain; self-loops -> INF
#pragma unroll
    for (int q = 0; q < 4; ++q) {
        int e = t + q * 256;
        int u = edges[2 * (g * EDGES + e)]     - g * NODES;
        int w = edges[2 * (g * EDGES + e) + 1] - g * NODES;
        if (u == w) { eks[hs][e] = INF32; }
        else {
            int ra = rank_[hs][u], rb = rank_[hs][w];
            int rlo = ra < rb ? ra : rb, rhi = ra < rb ? rb : ra;
            eks[hs][e] = ((unsigned)rhi << 18) | ((unsigned)e << 8) | (unsigned)rlo;
        }
        mstflag[hs][e] = 0;
    }
    __syncthreads();

    // Boruvka with early exit, intra-comp pruning, convergence jumping
    for (int round = 0; round < 8; ++round) {
        minE[hs][t] = INF32;
        if (tid == 0) chg = 0;
        __syncthreads();
#pragma unroll
        for (int q = 0; q < 4; ++q) {
            int e = t + q * 256;
            unsigned k = eks[hs][e];
            if (k != INF32) {
                int rlo = (int)(k & 255u), rhi = (int)(k >> 18);
                int cu = comp[hs][rlo], cv = comp[hs][rhi];
                if (cu != cv) {
                    atomicMin(&minE[hs][cu], k);
                    atomicMin(&minE[hs][cv], k);
                } else if (!mstflag[hs][e]) {
                    eks[hs][e] = INF32;   // prune: never merges again
                }
            }
        }
        __syncthreads();
        {
            unsigned mk = minE[hs][t];
            int o = t;
            if (mk != INF32) {
                int rlo = (int)(mk & 255u), rhi = (int)(mk >> 18);
                int cu = comp[hs][rlo], cv = comp[hs][rhi];
                o = (cu == t) ? cv : cu;
                mstflag[hs][(mk >> 8) & 0x3FFu] = 1;
                chg = 1;
            }
            nxt[hs][t] = o;
        }
        __syncthreads();
        if (!chg) break;
        {
            int o = nxt[hs][t];
            int p = o;
            if (nxt[hs][o] == t && t < o) p = t;
            par2[hs][t] = p;
        }
        __syncthreads();
        for (;;) {
            int p = par2[hs][par2[hs][t]];
            int done = __syncthreads_and(p == par2[hs][t]);
            if (done) break;
            par2[hs][t] = p;
            __syncthreads();
        }
        comp[hs][t] = par2[hs][comp[hs][t]];
        __syncthreads();
    }

    // collect MST edges (<=255 per sign)
    if (t == 0) cnt[hs] = 0;
    __syncthreads();
#pragma unroll
    for (int q = 0; q < 4; ++q) {
        int e = t + q * 256;
        if (mstflag[hs][e]) {
            int p = atomicAdd(&cnt[hs], 1);
            mstK[hs][p] = eks[hs][e];
        }
    }
    __syncthreads();
    if (t >= cnt[hs]) mstK[hs][t] = INF32;
    __syncthreads();

    // counting sort of MST keys (unique among valid)
    {
        unsigned myk2 = mstK[hs][t];
        if (myk2 != INF32) {
            int pos = 0;
#pragma unroll 8
            for (int j = 0; j < NODES; ++j) pos += (mstK[hs][j] < myk2) ? 1 : 0;
            srt[hs][pos] = myk2;
        }
    }
    __syncthreads();

    // wave-parallel Kruskal replay: wave 0 (hs=0) and wave 4 (hs=1) run
    // concurrently, each on its own registers + srt[hs]/cnt[hs].
    if (t < 64) {
        const int ln = t;
        int r0 = ln, r1 = 64 + ln, r2 = 128 + ln, r3 = 192 + ln;
        int d0 = -1, d1 = -1, d2 = -1, d3 = -1;
        int sv0 = (int)srt[hs][ln], sv1 = (int)srt[hs][ln + 64];
        int sv2 = (int)srt[hs][ln + 128], sv3 = (int)srt[hs][ln + 192];
        const int n = cnt[hs];
        for (int blk = 0; blk < 4; ++blk) {
            const int base = blk << 6;
            if (base >= n) break;
            int lim = n - base; if (lim > 64) lim = 64;
            const int svb = blk == 0 ? sv0 : blk == 1 ? sv1 : blk == 2 ? sv2 : sv3;
            for (int sl = 0; sl < lim; ++sl) {
                unsigned k = (unsigned)__builtin_amdgcn_readlane(svb, sl);
                const int rlo = (int)(k & 255u);
                const int rhi = (int)(k >> 18);
                const int jl = rlo >> 6, jh = rhi >> 6;
                const int cl = jl == 0 ? r0 : jl == 1 ? r1 : jl == 2 ? r2 : r3;
                const int a = __builtin_amdgcn_readlane(cl, rlo & 63);
                const int ch = jh == 0 ? r0 : jh == 1 ? r1 : jh == 2 ? r2 : r3;
                const int b = __builtin_amdgcn_readlane(ch, rhi & 63);
                if (a != b) {
                    const int elder = a < b ? a : b, young = a < b ? b : a;
                    r0 = (r0 == young) ? elder : r0;
                    r1 = (r1 == young) ? elder : r1;
                    r2 = (r2 == young) ? elder : r2;
                    r3 = (r3 == young) ? elder : r3;
                    const int jy = young >> 6;
                    const bool own = (ln == (young & 63));
                    if (jy == 0)      { if (own) d0 = rhi; }
                    else if (jy == 1) { if (own) d1 = rhi; }
                    else if (jy == 2) { if (own) d2 = rhi; }
                    else              { if (own) d3 = rhi; }
                }
            }
        }
        par[hs][ln] = r0; par[hs][ln + 64] = r1;
        par[hs][ln + 128] = r2; par[hs][ln + 192] = r3;
        dr[hs][ln] = d0; dr[hs][ln + 64] = d1;
        dr[hs][ln + 128] = d2; dr[hs][ln + 192] = d3;
    }
    __syncthreads();

    // component max (extended persistence); par is already the root
    {
        const int r = par[hs][t];
        atomicMax(&cmaxr[hs][r], t);
    }
    __syncthreads();
    {
        const int r = par[hs][t];
        float dvv = (dr[hs][t] >= 0) ? fvr[hs][dr[hs][t]] : fvr[hs][cmaxr[hs][r]];
        dsv[hs][order_[hs][t]] = dvv;   // original vertex order
    }
    __syncthreads();

    // ---- fused head: phi-MLPs + pooling (node loop split by half) --------
    {
        const float w00 = wp0[t], w01 = wp0[HP + t], bb0 = bp0[t];
        const float w10 = wp1[t], w11 = wp1[HP + t], bb1 = bp1[t];
        float s0 = 0.f, s1 = 0.f;
        const int n0 = hs * 128;
        for (int n = n0; n < n0 + 128; ++n) {
            float f = fv[0][n], dd0 = dsv[0][n], dd1 = dsv[1][n];
            float a0 = fmaf(f, w00, fmaf(dd0, w01, bb0));    // h0 = (f, d_sub)
            float a1 = fmaf(-dd1, w10, fmaf(f, w11, bb1));   // h1 = (-d_sup, f)
            s0 += a0 > 0.f ? a0 : 0.f;
            s1 += a1 > 0.f ? a1 : 0.f;
        }
        sred0[tid] = s0; sred1[tid] = s1;
    }
    __syncthreads();
    if (tid < 256) {
        const int lane = tid & 63, wv = tid >> 6;
        float s0 = sred0[tid] + sred0[tid + 256];
        float s1 = sred1[tid] + sred1[tid + 256];
        float pc[NC];
        const float* whr0 = wh + (size_t)tid * NC;
        const float* whr1 = wh + (size_t)(HP + tid) * NC;
#pragma unroll
        for (int c = 0; c < NC; ++c) pc[c] = s0 * whr0[c] + s1 * whr1[c];
#pragma unroll
        for (int off = 32; off > 0; off >>= 1)
#pragma unroll
            for (int c = 0; c < NC; ++c) pc[c] += __shfl_xor(pc[c], off, 64);
        if (lane == 0)
#pragma unroll
            for (int c = 0; c < NC; ++c) wpart[wv][c] = pc[c];
    }
    __syncthreads();
    if (tid < NC)
        out[g * NC + tid] = bh[tid] + wpart[0][tid] + wpart[1][tid]
                          + wpart[2][tid] + wpart[3][tid];
}

extern "C" void kernel_launch(void* const* d_in, const int* in_sizes, int n_in,
                              void* d_out, int out_size, void* d_ws, size_t ws_size,
                              hipStream_t stream)
{
    const float* x   = (const float*)d_in[0];
    const int*   edg = (const int*)d_in[1];
    const float* w1  = (const float*)d_in[3];
    const float* b1  = (const float*)d_in[4];
    const float* w2  = (const float*)d_in[5];
    const float* b2  = (const float*)d_in[6];
    const float* wp0 = (const float*)d_in[7];
    const float* bp0 = (const float*)d_in[8];
    const float* wp1 = (const float*)d_in[9];
    const float* bp1 = (const float*)d_in[10];
    const float* wh  = (const float*)d_in[11];
    const float* bh  = (const float*)d_in[12];

    float* zbuf = (float*)d_ws;                       // [NTOT] f32 (pre-sigmoid)
    float* dbuf = zbuf + NTOT;                        // [2][NTOT] (unused in v15)
    unsigned short* w1f = (unsigned short*)(dbuf + 2 * NTOT);  // 1 MB bf16

    const size_t WS_REQ = (size_t)3 * NTOT * 4 + (size_t)HF * DF * 2 + 256;

    if (ws_size >= WS_REQ) {
        k_cvt_frag<<<256, 256, 0, stream>>>(w1, w1f);
        k_fil_mfma<<<256, 256, 0, stream>>>(x, w1f, b1, w2, zbuf);
    } else {
        k_fil     <<<NTOT / TN2, 256, 0, stream>>>(x, w1, b1, w2, zbuf);
    }
    k_pers_head<<<NUM_GRAPHS, 512, 0, stream>>>(edg, zbuf, b2, wp0, bp0,
                                                wp1, bp1, wh, bh,
                                                (float*)d_out);
}

// Round 12
// 187.117 us; speedup vs baseline: 1.1833x; 1.1833x over previous
//
#include <hip/hip_runtime.h>
#include <hip/hip_bf16.h>

#define NUM_GRAPHS 64
#define NODES 256
#define EDGES 1024
#define NTOT (NUM_GRAPHS * NODES) /* 16384 */
#define DF 512
#define HF 1024
#define HP 256
#define NC 10
#define INF32 0xFFFFFFFFu

typedef short bf16x8 __attribute__((ext_vector_type(8)));
typedef float f32x4 __attribute__((ext_vector_type(4)));

__device__ __forceinline__ unsigned short bf16r(float f) {
    __hip_bfloat16 h = __float2bfloat16(f);
    return *(unsigned short*)&h;
}
// monotone order-preserving encode for fp32 (bijection, works for +/-)
__device__ __forceinline__ unsigned encf(float x) {
    union { float f; unsigned u; } c; c.f = x;
    return (c.u & 0x80000000u) ? ~c.u : (c.u | 0x80000000u);
}

// ---- w1 (f32 [k][j]) -> w1f bf16, LANE-ORDERED MFMA B-fragment layout ----
// Element addr: ((cg*16 + t)*64 + lane)*8 shorts, lane = quad*16 + n16;
// lane holds B[k = t*32 + quad*8 + j][col = cg*16 + n16].
__global__ __launch_bounds__(256) void k_cvt_frag(
    const float* __restrict__ w1, unsigned short* __restrict__ w1f)
{
    __shared__ float ls[128 * 16];   // [kk][c], 8 KB
    const int tid = threadIdx.x;
    const int cg = blockIdx.x >> 2, kq = blockIdx.x & 3;
    const int c = tid & 15, kr = tid >> 4;
#pragma unroll
    for (int it = 0; it < 8; ++it) {
        int kk = it * 16 + kr;
        ls[kk * 16 + c] = w1[(size_t)(kq * 128 + kk) * HF + cg * 16 + c];
    }
    __syncthreads();
    const int tt = tid >> 6, n16 = tid & 15, q = (tid >> 4) & 3;
    unsigned short v[8];
#pragma unroll
    for (int j = 0; j < 8; ++j)
        v[j] = bf16r(ls[(tt * 32 + q * 8 + j) * 16 + n16]);
    size_t off = ((size_t)(cg * 16 + kq * 4 + tt) * 64 + (q * 16 + n16)) * 8;
#pragma unroll
    for (int j = 0; j < 8; ++j) w1f[off + j] = v[j];
}

// ------- Stage 1 (MFMA v6): zbuf = relu(x@W1+b1)@w2 (pre-b2/sigmoid) ------
// R9-proven reg-staged version.
__global__ __launch_bounds__(256, 1) void k_fil_mfma(
    const float* __restrict__ x, const unsigned short* __restrict__ w1f,
    const float* __restrict__ b1, const float* __restrict__ w2,
    float* __restrict__ zbuf)
{
    __shared__ unsigned short Bbuf[4 * 16 * 512];  // 4 x 16 KB
    __shared__ float zpart[4][32];
    const int tid = threadIdx.x;
    const int lane = tid & 63;
    const int wv = tid >> 6;            // 0..3
    const int l15 = lane & 15, quad = lane >> 4;
    const int half = wv >> 1;           // column half (32 cgs)
    const int rt = wv & 1;              // row 32-tile
    const int r0 = blockIdx.x * 64;
    const int rowA = r0 + rt * 32 + l15;
    const int rowB = rowA + 16;

    // A fragments for 32 rows: two 16-row tiles, f32 -> bf16 in regs
    bf16x8 A0[16], A1[16];
#pragma unroll
    for (int t = 0; t < 16; ++t) {
        const float* s0 = x + (size_t)rowA * DF + t * 32 + quad * 8;
        const float* s1 = x + (size_t)rowB * DF + t * 32 + quad * 8;
        float4 a = *(const float4*)s0, b = *(const float4*)(s0 + 4);
        float4 c = *(const float4*)s1, d = *(const float4*)(s1 + 4);
        A0[t][0]=(short)bf16r(a.x); A0[t][1]=(short)bf16r(a.y);
        A0[t][2]=(short)bf16r(a.z); A0[t][3]=(short)bf16r(a.w);
        A0[t][4]=(short)bf16r(b.x); A0[t][5]=(short)bf16r(b.y);
        A0[t][6]=(short)bf16r(b.z); A0[t][7]=(short)bf16r(b.w);
        A1[t][0]=(short)bf16r(c.x); A1[t][1]=(short)bf16r(c.y);
        A1[t][2]=(short)bf16r(c.z); A1[t][3]=(short)bf16r(c.w);
        A1[t][4]=(short)bf16r(d.x); A1[t][5]=(short)bf16r(d.y);
        A1[t][6]=(short)bf16r(d.z); A1[t][7]=(short)bf16r(d.w);
    }

    // staging: threads 0-127 stage half 0, 128-255 stage half 1 (8 uint4 ea)
    const int t128 = tid & 127;
    const int sh = tid >> 7;
    uint4 pf[8];
    {
        const uint4* s = (const uint4*)(w1f + (size_t)(sh * 32) * 8192);
#pragma unroll
        for (int j = 0; j < 8; ++j) pf[j] = s[t128 + j * 128];
        uint4* d = (uint4*)Bbuf + (sh * 2 + 0) * 1024;
#pragma unroll
        for (int j = 0; j < 8; ++j) d[t128 + j * 128] = pf[j];
    }
    __syncthreads();

    float s_[2][4] = {{0,0,0,0},{0,0,0,0}};

    for (int i = 0; i < 32; ++i) {
        const int par = i & 1;
        if (i < 31) {
            const uint4* s = (const uint4*)(w1f + (size_t)(sh * 32 + i + 1) * 8192);
#pragma unroll
            for (int j = 0; j < 8; ++j) pf[j] = s[t128 + j * 128];
        }
        const unsigned short* bb = Bbuf + (half * 2 + par) * 8192 + lane * 8;
        f32x4 a00={0,0,0,0}, a01={0,0,0,0}, a10={0,0,0,0}, a11={0,0,0,0};
#pragma unroll
        for (int t = 0; t < 8; ++t) {
            bf16x8 Bf0 = *(const bf16x8*)(bb + t * 512);
            bf16x8 Bf1 = *(const bf16x8*)(bb + (t + 8) * 512);
            a00 = __builtin_amdgcn_mfma_f32_16x16x32_bf16(A0[t], Bf0, a00, 0, 0, 0);
            a10 = __builtin_amdgcn_mfma_f32_16x16x32_bf16(A1[t], Bf0, a10, 0, 0, 0);
            a01 = __builtin_amdgcn_mfma_f32_16x16x32_bf16(A0[t + 8], Bf1, a01, 0, 0, 0);
            a11 = __builtin_amdgcn_mfma_f32_16x16x32_bf16(A1[t + 8], Bf1, a11, 0, 0, 0);
        }
        const int col = (half * 32 + i) * 16 + l15;
        const float b1c = b1[col], w2c = w2[col];
#pragma unroll
        for (int r = 0; r < 4; ++r) {
            float h0 = (a00[r] + a01[r]) + b1c; h0 = h0 > 0.f ? h0 : 0.f;
            s_[0][r] = fmaf(h0, w2c, s_[0][r]);
            float h1 = (a10[r] + a11[r]) + b1c; h1 = h1 > 0.f ? h1 : 0.f;
            s_[1][r] = fmaf(h1, w2c, s_[1][r]);
        }
        if (i < 31) {
            uint4* d = (uint4*)Bbuf + (sh * 2 + (par ^ 1)) * 1024;
#pragma unroll
            for (int j = 0; j < 8; ++j) d[t128 + j * 128] = pf[j];
        }
        __syncthreads();
    }

    // reduce over 16 col-lanes; publish per-wave partials; join halves
#pragma unroll
    for (int sub = 0; sub < 2; ++sub)
#pragma unroll
        for (int r = 0; r < 4; ++r) {
            float v = s_[sub][r];
            v += __shfl_xor(v, 1, 16);
            v += __shfl_xor(v, 2, 16);
            v += __shfl_xor(v, 4, 16);
            v += __shfl_xor(v, 8, 16);
            if (l15 == 0) zpart[wv][sub * 16 + quad * 4 + r] = v;
        }
    __syncthreads();
    if (tid < 64) {
        int rrt = tid >> 5, idx = tid & 31;
        zbuf[r0 + tid] = zpart[rrt][idx] + zpart[rrt + 2][idx];
    }
}

// ---------------- Stage 1 legacy (fp32 VALU) — ws_size fallback -----------
#define TN2 16
__global__ __launch_bounds__(256) void k_fil(
    const float* __restrict__ x, const float* __restrict__ w1,
    const float* __restrict__ b1, const float* __restrict__ w2,
    float* __restrict__ zout)
{
    __shared__ float xs[TN2][DF];
    __shared__ float part[256];
    const int tid = threadIdx.x;
    const int n0 = blockIdx.x * TN2;
    for (int c = tid; c < TN2 * DF / 4; c += 256) {
        int n = c >> 7, k4 = (c & 127) << 2;
        *(float4*)&xs[n][k4] = *(const float4*)(x + (size_t)(n0 + n) * DF + k4);
    }
    __syncthreads();
    float h[TN2][4];
#pragma unroll
    for (int n = 0; n < TN2; ++n)
#pragma unroll
        for (int q = 0; q < 4; ++q) h[n][q] = 0.f;
    for (int k = 0; k < DF; ++k) {
        float wr[4];
#pragma unroll
        for (int q = 0; q < 4; ++q) wr[q] = w1[(size_t)k * HF + tid + 256 * q];
#pragma unroll
        for (int n = 0; n < TN2; ++n) {
            float xv = xs[n][k];
#pragma unroll
            for (int q = 0; q < 4; ++q) h[n][q] = fmaf(xv, wr[q], h[n][q]);
        }
    }
    float b1r[4], w2r[4];
#pragma unroll
    for (int q = 0; q < 4; ++q) { b1r[q] = b1[tid + 256 * q]; w2r[q] = w2[tid + 256 * q]; }
    for (int n = 0; n < TN2; ++n) {
        float s = 0.f;
#pragma unroll
        for (int q = 0; q < 4; ++q) {
            float hv = h[n][q] + b1r[q];
            s += (hv > 0.f ? hv : 0.f) * w2r[q];
        }
        part[tid] = s;
        __syncthreads();
        for (int off = 128; off > 0; off >>= 1) {
            if (tid < off) part[tid] += part[tid + off];
            __syncthreads();
        }
        if (tid == 0) zout[n0 + n] = part[0];
        __syncthreads();
    }
}

// -- Stage 2 (v16): v13 Boruvka (512 thr) + SWAR replay + connected-exit ---
// Changes vs R9/v13 (71.0us):
//  * replay body: v11-proven SWAR form (~240 cyc/edge vs v7-shape ~290):
//    all 256 roots in ONE u32/lane of wave 0 (byte j = root of 64j+ln);
//    find = readlane + uniform shift; union = branchless exact byte-replace;
//    deaths in dpack (byte = death rank, 0 = unpaired; rank 0 can never be
//    a death since rhi > rlo >= 0). v7 key decode: rhi needs &255 (e-bits
//    sit above bit 18).
//  * connected early-exit: when all comp equal, no further merges are
//    possible -> skip the final no-change Boruvka round.
__global__ __launch_bounds__(512) void k_pers(
    const int* __restrict__ edges, const float* __restrict__ zbuf,
    const float* __restrict__ b2, float* __restrict__ dout /* [2][NTOT] */)
{
    const int bid = blockIdx.x;
    const int g = bid >> 1, sgn = bid & 1;
    const int tid = threadIdx.x;        // 0..511
    const int v = tid & 255, vh = tid >> 8;

    __shared__ float fv[NODES];
    __shared__ unsigned long long vkey[NODES];
    __shared__ int order_[NODES], rank_[NODES];
    __shared__ float fvr[NODES];
    __shared__ unsigned eks[EDGES];
    __shared__ int comp[NODES];
    __shared__ unsigned minE[NODES];
    __shared__ int nxt[NODES], par2[NODES];
    __shared__ unsigned char mstflag[EDGES];
    __shared__ int cnt, chg;
    __shared__ unsigned mstK[NODES], srt[NODES];
    __shared__ int par[NODES], dr[NODES], cmaxr[NODES];
    __shared__ int rkp[512];

    if (tid < 256) {
        float z0 = zbuf[g * NODES + tid];
        float f0 = 1.f / (1.f + expf(-(z0 + b2[0])));
        fv[tid] = sgn ? -f0 : f0;
        vkey[tid] = ((unsigned long long)encf(fv[tid]) << 32) | (unsigned)tid;
        srt[tid] = INF32; dr[tid] = 0; cmaxr[tid] = 0; par[tid] = tid;
        comp[tid] = tid;
    }
    __syncthreads();

    // split counting rank: (v, vh) counts keys in [vh*128, vh*128+128)
    {
        const unsigned long long mk = vkey[v];
        const int j0 = vh << 7;
        int c = 0;
#pragma unroll 8
        for (int j = j0; j < j0 + 128; ++j) c += (vkey[j] < mk) ? 1 : 0;
        rkp[tid] = c;
    }
    __syncthreads();
    if (tid < 256) {
        int rk = rkp[tid] + rkp[tid + 256];
        order_[rk] = tid;
        rank_[tid] = rk;
        fvr[rk] = fv[tid];
    }
    __syncthreads();

    // edge keys in rank domain; self-loops -> INF (2 edges/thread)
#pragma unroll
    for (int q = 0; q < 2; ++q) {
        int e = tid + q * 512;
        int u = edges[2 * (g * EDGES + e)]     - g * NODES;
        int w = edges[2 * (g * EDGES + e) + 1] - g * NODES;
        if (u == w) { eks[e] = INF32; }
        else {
            int ra = rank_[u], rb = rank_[w];
            int rlo = ra < rb ? ra : rb, rhi = ra < rb ? rb : ra;
            eks[e] = ((unsigned)rhi << 18) | ((unsigned)e << 8) | (unsigned)rlo;
        }
        mstflag[e] = 0;
    }
    __syncthreads();

    // Boruvka with early exit, intra-comp pruning, convergence jumping
    for (int round = 0; round < 8; ++round) {
        if (tid < 256) minE[tid] = INF32;
        if (tid == 0) chg = 0;
        __syncthreads();
#pragma unroll
        for (int q = 0; q < 2; ++q) {
            int e = tid + q * 512;
            unsigned k = eks[e];
            if (k != INF32) {
                int rlo = (int)(k & 255u), rhi = (int)(k >> 18);
                int cu = comp[rlo], cv = comp[rhi];
                if (cu != cv) {
                    atomicMin(&minE[cu], k);
                    atomicMin(&minE[cv], k);
                } else if (!mstflag[e]) {
                    eks[e] = INF32;   // prune: never merges again
                }
            }
        }
        __syncthreads();
        if (tid < 256) {
            unsigned mk = minE[tid];
            int o = tid;
            if (mk != INF32) {
                int rlo = (int)(mk & 255u), rhi = (int)(mk >> 18);
                int cu = comp[rlo], cv = comp[rhi];
                o = (cu == tid) ? cv : cu;
                mstflag[(mk >> 8) & 0x3FFu] = 1;
                chg = 1;
            }
            nxt[tid] = o;
        }
        __syncthreads();
        if (!chg) break;
        if (tid < 256) {
            int o = nxt[tid];
            int p = o;
            if (nxt[o] == tid && tid < o) p = tid;
            par2[tid] = p;
        }
        __syncthreads();
        for (;;) {
            int p = par2[par2[v]];              // duplicated on both halves
            int done = __syncthreads_and(p == par2[v]);
            if (done) break;
            par2[v] = p;                        // benign same-value race
            __syncthreads();
        }
        if (tid < 256) comp[tid] = par2[comp[tid]];
        __syncthreads();
        // connected early-exit: single component => no merges remain
        if (__syncthreads_and(comp[v] == comp[0])) break;
    }

    // collect MST edges (<=255)
    if (tid == 0) cnt = 0;
    __syncthreads();
#pragma unroll
    for (int q = 0; q < 2; ++q) {
        int e = tid + q * 512;
        if (mstflag[e]) {
            int p = atomicAdd(&cnt, 1);
            mstK[p] = eks[e];
        }
    }
    __syncthreads();
    if (tid < 256 && tid >= cnt) mstK[tid] = INF32;
    __syncthreads();

    // split counting sort of MST keys (unique among valid)
    {
        const unsigned m2 = mstK[v];
        const int j0 = vh << 7;
        int c = 0;
        if (m2 != INF32) {
#pragma unroll 8
            for (int j = j0; j < j0 + 128; ++j) c += (mstK[j] < m2) ? 1 : 0;
        }
        rkp[tid] = c;
    }
    __syncthreads();
    if (tid < 256) {
        unsigned m2 = mstK[tid];
        if (m2 != INF32) srt[rkp[tid] + rkp[tid + 256]] = m2;
    }
    __syncthreads();

    // SWAR replay on wave 0 (v11-proven body, v7 key decode)
    if (tid < 64) {
        const int ln = tid;
        unsigned rpack = (unsigned)ln * 0x01010101u + 0xC0804000u;
        unsigned dpack = 0u;
        int sv0 = (int)srt[ln], sv1 = (int)srt[ln + 64];
        int sv2 = (int)srt[ln + 128], sv3 = (int)srt[ln + 192];
        const int n = cnt;
        for (int blk = 0; blk < 4; ++blk) {
            const int base = blk << 6;
            if (base >= n) break;
            int lim = n - base; if (lim > 64) lim = 64;
            const int svb = blk == 0 ? sv0 : blk == 1 ? sv1 : blk == 2 ? sv2 : sv3;
            for (int sl = 0; sl < lim; ++sl) {
                const unsigned k = (unsigned)__builtin_amdgcn_readlane(svb, sl);
                const int lo = (int)(k & 255u);
                const int hi = (int)((k >> 18) & 255u);
                const unsigned va = (unsigned)__builtin_amdgcn_readlane((int)rpack, lo & 63);
                const int ca = (int)((va >> ((lo >> 6) << 3)) & 255u);
                const unsigned vb = (unsigned)__builtin_amdgcn_readlane((int)rpack, hi & 63);
                const int cb = (int)((vb >> ((hi >> 6) << 3)) & 255u);
                const int elder = ca < cb ? ca : cb;
                const int young = ca > cb ? ca : cb;   // == elder if no merge
                // SWAR: replace bytes == young with elder (exact zero-detect)
                const unsigned y4 = (unsigned)young * 0x01010101u;
                const unsigned d4 = (unsigned)(young ^ elder) * 0x01010101u;
                const unsigned mm = rpack ^ y4;
                const unsigned ww = (mm | 0x80808080u) - 0x01010101u;
                const unsigned zm = ~(ww | mm) & 0x80808080u;
                rpack ^= d4 & ((zm >> 7) * 255u);
                // death of root `young` at rank `hi` (suppressed if no merge)
                const int merged = (ca != cb) ? 1 : 0;
                const int ysel = merged ? (young & 63) : 64;   // 64: no lane
                const unsigned shy = (unsigned)((young >> 6) << 3);
                const unsigned nd = (dpack & ~(255u << shy)) | ((unsigned)hi << shy);
                dpack = (ln == ysel) ? nd : dpack;
            }
        }
        par[ln]       = (int)(rpack & 255u);
        par[ln + 64]  = (int)((rpack >> 8) & 255u);
        par[ln + 128] = (int)((rpack >> 16) & 255u);
        par[ln + 192] = (int)(rpack >> 24);
        dr[ln]        = (int)(dpack & 255u);
        dr[ln + 64]   = (int)((dpack >> 8) & 255u);
        dr[ln + 128]  = (int)((dpack >> 16) & 255u);
        dr[ln + 192]  = (int)(dpack >> 24);
    }
    __syncthreads();

    // component max (extended persistence); par[tid] is already the root
    if (tid < 256) {
        const int r = par[tid];
        atomicMax(&cmaxr[r], tid);
    }
    __syncthreads();

    if (tid < 256) {
        const int r = par[tid];
        const int db = dr[tid];
        float dv = (db != 0) ? fvr[db] : fvr[cmaxr[r]];
        dout[sgn * NTOT + g * NODES + order_[tid]] = dv;
    }
}

// ------- Stage 3: per-pair MLPs + segment sum + linear head (fused) -------
__global__ __launch_bounds__(256) void k_head(
    const float* __restrict__ zbuf, const float* __restrict__ b2,
    const float* __restrict__ dbuf,
    const float* __restrict__ wp0, const float* __restrict__ bp0,
    const float* __restrict__ wp1, const float* __restrict__ bp1,
    const float* __restrict__ wh, const float* __restrict__ bh,
    float* __restrict__ out)
{
    const int g = blockIdx.x, tid = threadIdx.x;
    const int lane = tid & 63, wv = tid >> 6;
    __shared__ float lf[NODES], l0[NODES], l1[NODES];
    __shared__ float wpart[4][NC];
    lf[tid] = 1.f / (1.f + expf(-(zbuf[g * NODES + tid] + b2[0])));
    l0[tid] = dbuf[g * NODES + tid];
    l1[tid] = dbuf[NTOT + g * NODES + tid];
    __syncthreads();
    const float w00 = wp0[tid], w01 = wp0[HP + tid], bb0 = bp0[tid];
    const float w10 = wp1[tid], w11 = wp1[HP + tid], bb1 = bp1[tid];
    float s0 = 0.f, s1 = 0.f;
    for (int n = 0; n < NODES; ++n) {
        float f = lf[n], d0 = l0[n], d1 = l1[n];
        float a0 = fmaf(f, w00, fmaf(d0, w01, bb0));      // h0 = (f, d_sub)
        float a1 = fmaf(-d1, w10, fmaf(f, w11, bb1));     // h1 = (-d_sup, f)
        s0 += a0 > 0.f ? a0 : 0.f;
        s1 += a1 > 0.f ? a1 : 0.f;
    }
    // parallel head: thread tid holds pooled phi0[tid], phi1[tid]
    float pc[NC];
    const float* whr0 = wh + (size_t)tid * NC;
    const float* whr1 = wh + (size_t)(HP + tid) * NC;
#pragma unroll
    for (int c = 0; c < NC; ++c) pc[c] = s0 * whr0[c] + s1 * whr1[c];
#pragma unroll
    for (int off = 32; off > 0; off >>= 1)
#pragma unroll
        for (int c = 0; c < NC; ++c) pc[c] += __shfl_xor(pc[c], off, 64);
    if (lane == 0)
#pragma unroll
        for (int c = 0; c < NC; ++c) wpart[wv][c] = pc[c];
    __syncthreads();
    if (tid < NC)
        out[g * NC + tid] = bh[tid] + wpart[0][tid] + wpart[1][tid]
                          + wpart[2][tid] + wpart[3][tid];
}

extern "C" void kernel_launch(void* const* d_in, const int* in_sizes, int n_in,
                              void* d_out, int out_size, void* d_ws, size_t ws_size,
                              hipStream_t stream)
{
    const float* x   = (const float*)d_in[0];
    const int*   edg = (const int*)d_in[1];
    const float* w1  = (const float*)d_in[3];
    const float* b1  = (const float*)d_in[4];
    const float* w2  = (const float*)d_in[5];
    const float* b2  = (const float*)d_in[6];
    const float* wp0 = (const float*)d_in[7];
    const float* bp0 = (const float*)d_in[8];
    const float* wp1 = (const float*)d_in[9];
    const float* bp1 = (const float*)d_in[10];
    const float* wh  = (const float*)d_in[11];
    const float* bh  = (const float*)d_in[12];

    float* zbuf = (float*)d_ws;                       // [NTOT] f32 (pre-sigmoid)
    float* dbuf = zbuf + NTOT;                        // [2][NTOT] f32
    unsigned short* w1f = (unsigned short*)(dbuf + 2 * NTOT);  // 1 MB bf16

    const size_t WS_REQ = (size_t)3 * NTOT * 4 + (size_t)HF * DF * 2 + 256;

    if (ws_size >= WS_REQ) {
        k_cvt_frag<<<256, 256, 0, stream>>>(w1, w1f);
        k_fil_mfma<<<256, 256, 0, stream>>>(x, w1f, b1, w2, zbuf);
    } else {
        k_fil     <<<NTOT / TN2, 256, 0, stream>>>(x, w1, b1, w2, zbuf);
    }
    k_pers<<<NUM_GRAPHS * 2, 512, 0, stream>>>(edg, zbuf, b2, dbuf);
    k_head<<<NUM_GRAPHS, 256, 0, stream>>>(zbuf, b2, dbuf, wp0, bp0, wp1, bp1,
                                           wh, bh, (float*)d_out);
}

// Round 13
// 179.524 us; speedup vs baseline: 1.2333x; 1.0423x over previous
//
#include <hip/hip_runtime.h>
#include <hip/hip_bf16.h>

#define NUM_GRAPHS 64
#define NODES 256
#define EDGES 1024
#define NTOT (NUM_GRAPHS * NODES) /* 16384 */
#define DF 512
#define HF 1024
#define HP 256
#define NC 10
#define INF32 0xFFFFFFFFu

typedef short bf16x8 __attribute__((ext_vector_type(8)));
typedef float f32x4 __attribute__((ext_vector_type(4)));

__device__ __forceinline__ unsigned short bf16r(float f) {
    __hip_bfloat16 h = __float2bfloat16(f);
    return *(unsigned short*)&h;
}
// monotone order-preserving encode for fp32 (bijection, works for +/-)
__device__ __forceinline__ unsigned encf(float x) {
    union { float f; unsigned u; } c; c.f = x;
    return (c.u & 0x80000000u) ? ~c.u : (c.u | 0x80000000u);
}

// ---- w1 (f32 [k][j]) -> w1f bf16, LANE-ORDERED MFMA B-fragment layout ----
// Element addr: ((cg*16 + t)*64 + lane)*8 shorts, lane = quad*16 + n16;
// lane holds B[k = t*32 + quad*8 + j][col = cg*16 + n16].
__global__ __launch_bounds__(256) void k_cvt_frag(
    const float* __restrict__ w1, unsigned short* __restrict__ w1f)
{
    __shared__ float ls[128 * 16];   // [kk][c], 8 KB
    const int tid = threadIdx.x;
    const int cg = blockIdx.x >> 2, kq = blockIdx.x & 3;
    const int c = tid & 15, kr = tid >> 4;
#pragma unroll
    for (int it = 0; it < 8; ++it) {
        int kk = it * 16 + kr;
        ls[kk * 16 + c] = w1[(size_t)(kq * 128 + kk) * HF + cg * 16 + c];
    }
    __syncthreads();
    const int tt = tid >> 6, n16 = tid & 15, q = (tid >> 4) & 3;
    unsigned short v[8];
#pragma unroll
    for (int j = 0; j < 8; ++j)
        v[j] = bf16r(ls[(tt * 32 + q * 8 + j) * 16 + n16]);
    size_t off = ((size_t)(cg * 16 + kq * 4 + tt) * 64 + (q * 16 + n16)) * 8;
#pragma unroll
    for (int j = 0; j < 8; ++j) w1f[off + j] = v[j];
}

// ------- Stage 1 (MFMA v8): zbuf = relu(x@W1+b1)@w2 partials -------------
// v17: grid 256 -> 512 blocks (2 blocks/CU). Block b: rows (b>>1)*64,
// column half ch=b&1 (32 cgs, 16 iters). R12 showed Occupancy 9.9% (1
// block/CU) with 75% of each iteration as exposed latency; 2 blocks/CU
// overlaps the chains (m114). Each block writes its 512-col partial to
// zbuf plane ch; consumers add the planes (same grouping as the old
// intra-block half-join, deterministic).
__global__ __launch_bounds__(256, 1) void k_fil_mfma(
    const float* __restrict__ x, const unsigned short* __restrict__ w1f,
    const float* __restrict__ b1, const float* __restrict__ w2,
    float* __restrict__ zbuf /* [2][NTOT] */)
{
    __shared__ unsigned short Bbuf[4 * 16 * 512];  // 4 x 16 KB
    __shared__ float zpart[4][32];
    const int tid = threadIdx.x;
    const int lane = tid & 63;
    const int wv = tid >> 6;            // 0..3
    const int l15 = lane & 15, quad = lane >> 4;
    const int half = wv >> 1;           // sub-half (16 cgs) within block
    const int rt = wv & 1;              // row 32-tile
    const int r0 = (blockIdx.x >> 1) * 64;
    const int ch = blockIdx.x & 1;      // block column half
    const int cg0 = ch * 32;            // first cg of this block
    const int rowA = r0 + rt * 32 + l15;
    const int rowB = rowA + 16;

    // A fragments for 32 rows: two 16-row tiles, f32 -> bf16 in regs
    bf16x8 A0[16], A1[16];
#pragma unroll
    for (int t = 0; t < 16; ++t) {
        const float* s0 = x + (size_t)rowA * DF + t * 32 + quad * 8;
        const float* s1 = x + (size_t)rowB * DF + t * 32 + quad * 8;
        float4 a = *(const float4*)s0, b = *(const float4*)(s0 + 4);
        float4 c = *(const float4*)s1, d = *(const float4*)(s1 + 4);
        A0[t][0]=(short)bf16r(a.x); A0[t][1]=(short)bf16r(a.y);
        A0[t][2]=(short)bf16r(a.z); A0[t][3]=(short)bf16r(a.w);
        A0[t][4]=(short)bf16r(b.x); A0[t][5]=(short)bf16r(b.y);
        A0[t][6]=(short)bf16r(b.z); A0[t][7]=(short)bf16r(b.w);
        A1[t][0]=(short)bf16r(c.x); A1[t][1]=(short)bf16r(c.y);
        A1[t][2]=(short)bf16r(c.z); A1[t][3]=(short)bf16r(c.w);
        A1[t][4]=(short)bf16r(d.x); A1[t][5]=(short)bf16r(d.y);
        A1[t][6]=(short)bf16r(d.z); A1[t][7]=(short)bf16r(d.w);
    }

    // staging: threads 0-127 stage sub-half 0, 128-255 sub-half 1
    const int t128 = tid & 127;
    const int sh = tid >> 7;
    uint4 pf[8];
    {
        const uint4* s = (const uint4*)(w1f + (size_t)(cg0 + sh * 16) * 8192);
#pragma unroll
        for (int j = 0; j < 8; ++j) pf[j] = s[t128 + j * 128];
        uint4* d = (uint4*)Bbuf + (sh * 2 + 0) * 1024;
#pragma unroll
        for (int j = 0; j < 8; ++j) d[t128 + j * 128] = pf[j];
    }
    __syncthreads();

    float s_[2][4] = {{0,0,0,0},{0,0,0,0}};

    for (int i = 0; i < 16; ++i) {
        const int par = i & 1;
        if (i < 15) {
            const uint4* s = (const uint4*)(w1f + (size_t)(cg0 + sh * 16 + i + 1) * 8192);
#pragma unroll
            for (int j = 0; j < 8; ++j) pf[j] = s[t128 + j * 128];
        }
        const unsigned short* bb = Bbuf + (half * 2 + par) * 8192 + lane * 8;
        f32x4 a00={0,0,0,0}, a01={0,0,0,0}, a10={0,0,0,0}, a11={0,0,0,0};
#pragma unroll
        for (int t = 0; t < 8; ++t) {
            bf16x8 Bf0 = *(const bf16x8*)(bb + t * 512);
            bf16x8 Bf1 = *(const bf16x8*)(bb + (t + 8) * 512);
            a00 = __builtin_amdgcn_mfma_f32_16x16x32_bf16(A0[t], Bf0, a00, 0, 0, 0);
            a10 = __builtin_amdgcn_mfma_f32_16x16x32_bf16(A1[t], Bf0, a10, 0, 0, 0);
            a01 = __builtin_amdgcn_mfma_f32_16x16x32_bf16(A0[t + 8], Bf1, a01, 0, 0, 0);
            a11 = __builtin_amdgcn_mfma_f32_16x16x32_bf16(A1[t + 8], Bf1, a11, 0, 0, 0);
        }
        const int col = (cg0 + half * 16 + i) * 16 + l15;
        const float b1c = b1[col], w2c = w2[col];
#pragma unroll
        for (int r = 0; r < 4; ++r) {
            float h0 = (a00[r] + a01[r]) + b1c; h0 = h0 > 0.f ? h0 : 0.f;
            s_[0][r] = fmaf(h0, w2c, s_[0][r]);
            float h1 = (a10[r] + a11[r]) + b1c; h1 = h1 > 0.f ? h1 : 0.f;
            s_[1][r] = fmaf(h1, w2c, s_[1][r]);
        }
        if (i < 15) {
            uint4* d = (uint4*)Bbuf + (sh * 2 + (par ^ 1)) * 1024;
#pragma unroll
            for (int j = 0; j < 8; ++j) d[t128 + j * 128] = pf[j];
        }
        __syncthreads();
    }

    // reduce over 16 col-lanes; publish per-wave partials; join sub-halves
#pragma unroll
    for (int sub = 0; sub < 2; ++sub)
#pragma unroll
        for (int r = 0; r < 4; ++r) {
            float v = s_[sub][r];
            v += __shfl_xor(v, 1, 16);
            v += __shfl_xor(v, 2, 16);
            v += __shfl_xor(v, 4, 16);
            v += __shfl_xor(v, 8, 16);
            if (l15 == 0) zpart[wv][sub * 16 + quad * 4 + r] = v;
        }
    __syncthreads();
    if (tid < 64) {
        int rrt = tid >> 5, idx = tid & 31;
        zbuf[(size_t)ch * NTOT + r0 + tid] = zpart[rrt][idx] + zpart[rrt + 2][idx];
    }
}

// ---------------- Stage 1 legacy (fp32 VALU) — ws_size fallback -----------
#define TN2 16
__global__ __launch_bounds__(256) void k_fil(
    const float* __restrict__ x, const float* __restrict__ w1,
    const float* __restrict__ b1, const float* __restrict__ w2,
    float* __restrict__ zout)
{
    __shared__ float xs[TN2][DF];
    __shared__ float part[256];
    const int tid = threadIdx.x;
    const int n0 = blockIdx.x * TN2;
    for (int c = tid; c < TN2 * DF / 4; c += 256) {
        int n = c >> 7, k4 = (c & 127) << 2;
        *(float4*)&xs[n][k4] = *(const float4*)(x + (size_t)(n0 + n) * DF + k4);
    }
    __syncthreads();
    float h[TN2][4];
#pragma unroll
    for (int n = 0; n < TN2; ++n)
#pragma unroll
        for (int q = 0; q < 4; ++q) h[n][q] = 0.f;
    for (int k = 0; k < DF; ++k) {
        float wr[4];
#pragma unroll
        for (int q = 0; q < 4; ++q) wr[q] = w1[(size_t)k * HF + tid + 256 * q];
#pragma unroll
        for (int n = 0; n < TN2; ++n) {
            float xv = xs[n][k];
#pragma unroll
            for (int q = 0; q < 4; ++q) h[n][q] = fmaf(xv, wr[q], h[n][q]);
        }
    }
    float b1r[4], w2r[4];
#pragma unroll
    for (int q = 0; q < 4; ++q) { b1r[q] = b1[tid + 256 * q]; w2r[q] = w2[tid + 256 * q]; }
    for (int n = 0; n < TN2; ++n) {
        float s = 0.f;
#pragma unroll
        for (int q = 0; q < 4; ++q) {
            float hv = h[n][q] + b1r[q];
            s += (hv > 0.f ? hv : 0.f) * w2r[q];
        }
        part[tid] = s;
        __syncthreads();
        for (int off = 128; off > 0; off >>= 1) {
            if (tid < off) part[tid] += part[tid + off];
            __syncthreads();
        }
        if (tid == 0) zout[n0 + n] = part[0];
        __syncthreads();
    }
}

// -- Stage 2 (v16): v13 Boruvka (512 thr) + SWAR replay + connected-exit ---
// v17: reads z as sum of the two column-half planes.
__global__ __launch_bounds__(512) void k_pers(
    const int* __restrict__ edges, const float* __restrict__ zbuf,
    const float* __restrict__ b2, float* __restrict__ dout /* [2][NTOT] */)
{
    const int bid = blockIdx.x;
    const int g = bid >> 1, sgn = bid & 1;
    const int tid = threadIdx.x;        // 0..511
    const int v = tid & 255, vh = tid >> 8;

    __shared__ float fv[NODES];
    __shared__ unsigned long long vkey[NODES];
    __shared__ int order_[NODES], rank_[NODES];
    __shared__ float fvr[NODES];
    __shared__ unsigned eks[EDGES];
    __shared__ int comp[NODES];
    __shared__ unsigned minE[NODES];
    __shared__ int nxt[NODES], par2[NODES];
    __shared__ unsigned char mstflag[EDGES];
    __shared__ int cnt, chg;
    __shared__ unsigned mstK[NODES], srt[NODES];
    __shared__ int par[NODES], dr[NODES], cmaxr[NODES];
    __shared__ int rkp[512];

    if (tid < 256) {
        float z0 = zbuf[g * NODES + tid] + zbuf[NTOT + g * NODES + tid];
        float f0 = 1.f / (1.f + expf(-(z0 + b2[0])));
        fv[tid] = sgn ? -f0 : f0;
        vkey[tid] = ((unsigned long long)encf(fv[tid]) << 32) | (unsigned)tid;
        srt[tid] = INF32; dr[tid] = 0; cmaxr[tid] = 0; par[tid] = tid;
        comp[tid] = tid;
    }
    __syncthreads();

    // split counting rank: (v, vh) counts keys in [vh*128, vh*128+128)
    {
        const unsigned long long mk = vkey[v];
        const int j0 = vh << 7;
        int c = 0;
#pragma unroll 8
        for (int j = j0; j < j0 + 128; ++j) c += (vkey[j] < mk) ? 1 : 0;
        rkp[tid] = c;
    }
    __syncthreads();
    if (tid < 256) {
        int rk = rkp[tid] + rkp[tid + 256];
        order_[rk] = tid;
        rank_[tid] = rk;
        fvr[rk] = fv[tid];
    }
    __syncthreads();

    // edge keys in rank domain; self-loops -> INF (2 edges/thread)
#pragma unroll
    for (int q = 0; q < 2; ++q) {
        int e = tid + q * 512;
        int u = edges[2 * (g * EDGES + e)]     - g * NODES;
        int w = edges[2 * (g * EDGES + e) + 1] - g * NODES;
        if (u == w) { eks[e] = INF32; }
        else {
            int ra = rank_[u], rb = rank_[w];
            int rlo = ra < rb ? ra : rb, rhi = ra < rb ? rb : ra;
            eks[e] = ((unsigned)rhi << 18) | ((unsigned)e << 8) | (unsigned)rlo;
        }
        mstflag[e] = 0;
    }
    __syncthreads();

    // Boruvka with early exit, intra-comp pruning, convergence jumping
    for (int round = 0; round < 8; ++round) {
        if (tid < 256) minE[tid] = INF32;
        if (tid == 0) chg = 0;
        __syncthreads();
#pragma unroll
        for (int q = 0; q < 2; ++q) {
            int e = tid + q * 512;
            unsigned k = eks[e];
            if (k != INF32) {
                int rlo = (int)(k & 255u), rhi = (int)(k >> 18);
                int cu = comp[rlo], cv = comp[rhi];
                if (cu != cv) {
                    atomicMin(&minE[cu], k);
                    atomicMin(&minE[cv], k);
                } else if (!mstflag[e]) {
                    eks[e] = INF32;   // prune: never merges again
                }
            }
        }
        __syncthreads();
        if (tid < 256) {
            unsigned mk = minE[tid];
            int o = tid;
            if (mk != INF32) {
                int rlo = (int)(mk & 255u), rhi = (int)(mk >> 18);
                int cu = comp[rlo], cv = comp[rhi];
                o = (cu == tid) ? cv : cu;
                mstflag[(mk >> 8) & 0x3FFu] = 1;
                chg = 1;
            }
            nxt[tid] = o;
        }
        __syncthreads();
        if (!chg) break;
        if (tid < 256) {
            int o = nxt[tid];
            int p = o;
            if (nxt[o] == tid && tid < o) p = tid;
            par2[tid] = p;
        }
        __syncthreads();
        for (;;) {
            int p = par2[par2[v]];              // duplicated on both halves
            int done = __syncthreads_and(p == par2[v]);
            if (done) break;
            par2[v] = p;                        // benign same-value race
            __syncthreads();
        }
        if (tid < 256) comp[tid] = par2[comp[tid]];
        __syncthreads();
        // connected early-exit: single component => no merges remain
        if (__syncthreads_and(comp[v] == comp[0])) break;
    }

    // collect MST edges (<=255)
    if (tid == 0) cnt = 0;
    __syncthreads();
#pragma unroll
    for (int q = 0; q < 2; ++q) {
        int e = tid + q * 512;
        if (mstflag[e]) {
            int p = atomicAdd(&cnt, 1);
            mstK[p] = eks[e];
        }
    }
    __syncthreads();
    if (tid < 256 && tid >= cnt) mstK[tid] = INF32;
    __syncthreads();

    // split counting sort of MST keys (unique among valid)
    {
        const unsigned m2 = mstK[v];
        const int j0 = vh << 7;
        int c = 0;
        if (m2 != INF32) {
#pragma unroll 8
            for (int j = j0; j < j0 + 128; ++j) c += (mstK[j] < m2) ? 1 : 0;
        }
        rkp[tid] = c;
    }
    __syncthreads();
    if (tid < 256) {
        unsigned m2 = mstK[tid];
        if (m2 != INF32) srt[rkp[tid] + rkp[tid + 256]] = m2;
    }
    __syncthreads();

    // SWAR replay on wave 0 (v11-proven body, v7 key decode)
    if (tid < 64) {
        const int ln = tid;
        unsigned rpack = (unsigned)ln * 0x01010101u + 0xC0804000u;
        unsigned dpack = 0u;
        int sv0 = (int)srt[ln], sv1 = (int)srt[ln + 64];
        int sv2 = (int)srt[ln + 128], sv3 = (int)srt[ln + 192];
        const int n = cnt;
        for (int blk = 0; blk < 4; ++blk) {
            const int base = blk << 6;
            if (base >= n) break;
            int lim = n - base; if (lim > 64) lim = 64;
            const int svb = blk == 0 ? sv0 : blk == 1 ? sv1 : blk == 2 ? sv2 : sv3;
            for (int sl = 0; sl < lim; ++sl) {
                const unsigned k = (unsigned)__builtin_amdgcn_readlane(svb, sl);
                const int lo = (int)(k & 255u);
                const int hi = (int)((k >> 18) & 255u);
                const unsigned va = (unsigned)__builtin_amdgcn_readlane((int)rpack, lo & 63);
                const int ca = (int)((va >> ((lo >> 6) << 3)) & 255u);
                const unsigned vb = (unsigned)__builtin_amdgcn_readlane((int)rpack, hi & 63);
                const int cb = (int)((vb >> ((hi >> 6) << 3)) & 255u);
                const int elder = ca < cb ? ca : cb;
                const int young = ca > cb ? ca : cb;   // == elder if no merge
                // SWAR: replace bytes == young with elder (exact zero-detect)
                const unsigned y4 = (unsigned)young * 0x01010101u;
                const unsigned d4 = (unsigned)(young ^ elder) * 0x01010101u;
                const unsigned mm = rpack ^ y4;
                const unsigned ww = (mm | 0x80808080u) - 0x01010101u;
                const unsigned zm = ~(ww | mm) & 0x80808080u;
                rpack ^= d4 & ((zm >> 7) * 255u);
                // death of root `young` at rank `hi` (suppressed if no merge)
                const int merged = (ca != cb) ? 1 : 0;
                const int ysel = merged ? (young & 63) : 64;   // 64: no lane
                const unsigned shy = (unsigned)((young >> 6) << 3);
                const unsigned nd = (dpack & ~(255u << shy)) | ((unsigned)hi << shy);
                dpack = (ln == ysel) ? nd : dpack;
            }
        }
        par[ln]       = (int)(rpack & 255u);
        par[ln + 64]  = (int)((rpack >> 8) & 255u);
        par[ln + 128] = (int)((rpack >> 16) & 255u);
        par[ln + 192] = (int)(rpack >> 24);
        dr[ln]        = (int)(dpack & 255u);
        dr[ln + 64]   = (int)((dpack >> 8) & 255u);
        dr[ln + 128]  = (int)((dpack >> 16) & 255u);
        dr[ln + 192]  = (int)(dpack >> 24);
    }
    __syncthreads();

    // component max (extended persistence); par[tid] is already the root
    if (tid < 256) {
        const int r = par[tid];
        atomicMax(&cmaxr[r], tid);
    }
    __syncthreads();

    if (tid < 256) {
        const int r = par[tid];
        const int db = dr[tid];
        float dv = (db != 0) ? fvr[db] : fvr[cmaxr[r]];
        dout[sgn * NTOT + g * NODES + order_[tid]] = dv;
    }
}

// ------- Stage 3: per-pair MLPs + segment sum + linear head (fused) -------
__global__ __launch_bounds__(256) void k_head(
    const float* __restrict__ zbuf, const float* __restrict__ b2,
    const float* __restrict__ dbuf,
    const float* __restrict__ wp0, const float* __restrict__ bp0,
    const float* __restrict__ wp1, const float* __restrict__ bp1,
    const float* __restrict__ wh, const float* __restrict__ bh,
    float* __restrict__ out)
{
    const int g = blockIdx.x, tid = threadIdx.x;
    const int lane = tid & 63, wv = tid >> 6;
    __shared__ float lf[NODES], l0[NODES], l1[NODES];
    __shared__ float wpart[4][NC];
    {
        float z0 = zbuf[g * NODES + tid] + zbuf[NTOT + g * NODES + tid];
        lf[tid] = 1.f / (1.f + expf(-(z0 + b2[0])));
    }
    l0[tid] = dbuf[g * NODES + tid];
    l1[tid] = dbuf[NTOT + g * NODES + tid];
    __syncthreads();
    const float w00 = wp0[tid], w01 = wp0[HP + tid], bb0 = bp0[tid];
    const float w10 = wp1[tid], w11 = wp1[HP + tid], bb1 = bp1[tid];
    float s0 = 0.f, s1 = 0.f;
    for (int n = 0; n < NODES; ++n) {
        float f = lf[n], d0 = l0[n], d1 = l1[n];
        float a0 = fmaf(f, w00, fmaf(d0, w01, bb0));      // h0 = (f, d_sub)
        float a1 = fmaf(-d1, w10, fmaf(f, w11, bb1));     // h1 = (-d_sup, f)
        s0 += a0 > 0.f ? a0 : 0.f;
        s1 += a1 > 0.f ? a1 : 0.f;
    }
    // parallel head: thread tid holds pooled phi0[tid], phi1[tid]
    float pc[NC];
    const float* whr0 = wh + (size_t)tid * NC;
    const float* whr1 = wh + (size_t)(HP + tid) * NC;
#pragma unroll
    for (int c = 0; c < NC; ++c) pc[c] = s0 * whr0[c] + s1 * whr1[c];
#pragma unroll
    for (int off = 32; off > 0; off >>= 1)
#pragma unroll
        for (int c = 0; c < NC; ++c) pc[c] += __shfl_xor(pc[c], off, 64);
    if (lane == 0)
#pragma unroll
        for (int c = 0; c < NC; ++c) wpart[wv][c] = pc[c];
    __syncthreads();
    if (tid < NC)
        out[g * NC + tid] = bh[tid] + wpart[0][tid] + wpart[1][tid]
                          + wpart[2][tid] + wpart[3][tid];
}

extern "C" void kernel_launch(void* const* d_in, const int* in_sizes, int n_in,
                              void* d_out, int out_size, void* d_ws, size_t ws_size,
                              hipStream_t stream)
{
    const float* x   = (const float*)d_in[0];
    const int*   edg = (const int*)d_in[1];
    const float* w1  = (const float*)d_in[3];
    const float* b1  = (const float*)d_in[4];
    const float* w2  = (const float*)d_in[5];
    const float* b2  = (const float*)d_in[6];
    const float* wp0 = (const float*)d_in[7];
    const float* bp0 = (const float*)d_in[8];
    const float* wp1 = (const float*)d_in[9];
    const float* bp1 = (const float*)d_in[10];
    const float* wh  = (const float*)d_in[11];
    const float* bh  = (const float*)d_in[12];

    float* zbuf = (float*)d_ws;                       // [2][NTOT] f32 partials
    float* dbuf = zbuf + 2 * NTOT;                    // [2][NTOT] f32
    unsigned short* w1f = (unsigned short*)(dbuf + 2 * NTOT);  // 1 MB bf16

    const size_t WS_REQ = (size_t)4 * NTOT * 4 + (size_t)HF * DF * 2 + 256;

    if (ws_size >= WS_REQ) {
        k_cvt_frag<<<256, 256, 0, stream>>>(w1, w1f);
        k_fil_mfma<<<512, 256, 0, stream>>>(x, w1f, b1, w2, zbuf);
    } else {
        // fallback: plane 0 from k_fil, plane 1 zeroed
        hipMemsetAsync(zbuf + NTOT, 0, (size_t)NTOT * 4, stream);
        k_fil     <<<NTOT / TN2, 256, 0, stream>>>(x, w1, b1, w2, zbuf);
    }
    k_pers<<<NUM_GRAPHS * 2, 512, 0, stream>>>(edg, zbuf, b2, dbuf);
    k_head<<<NUM_GRAPHS, 256, 0, stream>>>(zbuf, b2, dbuf, wp0, bp0, wp1, bp1,
                                           wh, bh, (float*)d_out);
}

// Round 14
// 174.263 us; speedup vs baseline: 1.2706x; 1.0302x over previous
//
#include <hip/hip_runtime.h>
#include <hip/hip_bf16.h>

#define NUM_GRAPHS 64
#define NODES 256
#define EDGES 1024
#define NTOT (NUM_GRAPHS * NODES) /* 16384 */
#define DF 512
#define HF 1024
#define HP 256
#define NC 10
#define INF32 0xFFFFFFFFu

typedef short bf16x8 __attribute__((ext_vector_type(8)));
typedef float f32x4 __attribute__((ext_vector_type(4)));

__device__ __forceinline__ unsigned short bf16r(float f) {
    __hip_bfloat16 h = __float2bfloat16(f);
    return *(unsigned short*)&h;
}
// monotone order-preserving encode for fp32 (bijection, works for +/-)
__device__ __forceinline__ unsigned encf(float x) {
    union { float f; unsigned u; } c; c.f = x;
    return (c.u & 0x80000000u) ? ~c.u : (c.u | 0x80000000u);
}

// ---- w1 (f32 [k][j]) -> w1f bf16, LANE-ORDERED MFMA B-fragment layout ----
__global__ __launch_bounds__(256) void k_cvt_frag(
    const float* __restrict__ w1, unsigned short* __restrict__ w1f)
{
    __shared__ float ls[128 * 16];   // [kk][c], 8 KB
    const int tid = threadIdx.x;
    const int cg = blockIdx.x >> 2, kq = blockIdx.x & 3;
    const int c = tid & 15, kr = tid >> 4;
#pragma unroll
    for (int it = 0; it < 8; ++it) {
        int kk = it * 16 + kr;
        ls[kk * 16 + c] = w1[(size_t)(kq * 128 + kk) * HF + cg * 16 + c];
    }
    __syncthreads();
    const int tt = tid >> 6, n16 = tid & 15, q = (tid >> 4) & 3;
    unsigned short v[8];
#pragma unroll
    for (int j = 0; j < 8; ++j)
        v[j] = bf16r(ls[(tt * 32 + q * 8 + j) * 16 + n16]);
    size_t off = ((size_t)(cg * 16 + kq * 4 + tt) * 64 + (q * 16 + n16)) * 8;
#pragma unroll
    for (int j = 0; j < 8; ++j) w1f[off + j] = v[j];
}

// ------- Stage 1 (MFMA v8): zbuf = relu(x@W1+b1)@w2 partials -------------
// v17: 512 blocks (2/CU). Block b: rows (b>>1)*64, column half ch=b&1.
__global__ __launch_bounds__(256, 1) void k_fil_mfma(
    const float* __restrict__ x, const unsigned short* __restrict__ w1f,
    const float* __restrict__ b1, const float* __restrict__ w2,
    float* __restrict__ zbuf /* [2][NTOT] */)
{
    __shared__ unsigned short Bbuf[4 * 16 * 512];  // 4 x 16 KB
    __shared__ float zpart[4][32];
    const int tid = threadIdx.x;
    const int lane = tid & 63;
    const int wv = tid >> 6;            // 0..3
    const int l15 = lane & 15, quad = lane >> 4;
    const int half = wv >> 1;           // sub-half (16 cgs) within block
    const int rt = wv & 1;              // row 32-tile
    const int r0 = (blockIdx.x >> 1) * 64;
    const int ch = blockIdx.x & 1;      // block column half
    const int cg0 = ch * 32;            // first cg of this block
    const int rowA = r0 + rt * 32 + l15;
    const int rowB = rowA + 16;

    // A fragments for 32 rows: two 16-row tiles, f32 -> bf16 in regs
    bf16x8 A0[16], A1[16];
#pragma unroll
    for (int t = 0; t < 16; ++t) {
        const float* s0 = x + (size_t)rowA * DF + t * 32 + quad * 8;
        const float* s1 = x + (size_t)rowB * DF + t * 32 + quad * 8;
        float4 a = *(const float4*)s0, b = *(const float4*)(s0 + 4);
        float4 c = *(const float4*)s1, d = *(const float4*)(s1 + 4);
        A0[t][0]=(short)bf16r(a.x); A0[t][1]=(short)bf16r(a.y);
        A0[t][2]=(short)bf16r(a.z); A0[t][3]=(short)bf16r(a.w);
        A0[t][4]=(short)bf16r(b.x); A0[t][5]=(short)bf16r(b.y);
        A0[t][6]=(short)bf16r(b.z); A0[t][7]=(short)bf16r(b.w);
        A1[t][0]=(short)bf16r(c.x); A1[t][1]=(short)bf16r(c.y);
        A1[t][2]=(short)bf16r(c.z); A1[t][3]=(short)bf16r(c.w);
        A1[t][4]=(short)bf16r(d.x); A1[t][5]=(short)bf16r(d.y);
        A1[t][6]=(short)bf16r(d.z); A1[t][7]=(short)bf16r(d.w);
    }

    // staging: threads 0-127 stage sub-half 0, 128-255 sub-half 1
    const int t128 = tid & 127;
    const int sh = tid >> 7;
    uint4 pf[8];
    {
        const uint4* s = (const uint4*)(w1f + (size_t)(cg0 + sh * 16) * 8192);
#pragma unroll
        for (int j = 0; j < 8; ++j) pf[j] = s[t128 + j * 128];
        uint4* d = (uint4*)Bbuf + (sh * 2 + 0) * 1024;
#pragma unroll
        for (int j = 0; j < 8; ++j) d[t128 + j * 128] = pf[j];
    }
    __syncthreads();

    float s_[2][4] = {{0,0,0,0},{0,0,0,0}};

    for (int i = 0; i < 16; ++i) {
        const int par = i & 1;
        if (i < 15) {
            const uint4* s = (const uint4*)(w1f + (size_t)(cg0 + sh * 16 + i + 1) * 8192);
#pragma unroll
            for (int j = 0; j < 8; ++j) pf[j] = s[t128 + j * 128];
        }
        const unsigned short* bb = Bbuf + (half * 2 + par) * 8192 + lane * 8;
        f32x4 a00={0,0,0,0}, a01={0,0,0,0}, a10={0,0,0,0}, a11={0,0,0,0};
#pragma unroll
        for (int t = 0; t < 8; ++t) {
            bf16x8 Bf0 = *(const bf16x8*)(bb + t * 512);
            bf16x8 Bf1 = *(const bf16x8*)(bb + (t + 8) * 512);
            a00 = __builtin_amdgcn_mfma_f32_16x16x32_bf16(A0[t], Bf0, a00, 0, 0, 0);
            a10 = __builtin_amdgcn_mfma_f32_16x16x32_bf16(A1[t], Bf0, a10, 0, 0, 0);
            a01 = __builtin_amdgcn_mfma_f32_16x16x32_bf16(A0[t + 8], Bf1, a01, 0, 0, 0);
            a11 = __builtin_amdgcn_mfma_f32_16x16x32_bf16(A1[t + 8], Bf1, a11, 0, 0, 0);
        }
        const int col = (cg0 + half * 16 + i) * 16 + l15;
        const float b1c = b1[col], w2c = w2[col];
#pragma unroll
        for (int r = 0; r < 4; ++r) {
            float h0 = (a00[r] + a01[r]) + b1c; h0 = h0 > 0.f ? h0 : 0.f;
            s_[0][r] = fmaf(h0, w2c, s_[0][r]);
            float h1 = (a10[r] + a11[r]) + b1c; h1 = h1 > 0.f ? h1 : 0.f;
            s_[1][r] = fmaf(h1, w2c, s_[1][r]);
        }
        if (i < 15) {
            uint4* d = (uint4*)Bbuf + (sh * 2 + (par ^ 1)) * 1024;
#pragma unroll
            for (int j = 0; j < 8; ++j) d[t128 + j * 128] = pf[j];
        }
        __syncthreads();
    }

    // reduce over 16 col-lanes; publish per-wave partials; join sub-halves
#pragma unroll
    for (int sub = 0; sub < 2; ++sub)
#pragma unroll
        for (int r = 0; r < 4; ++r) {
            float v = s_[sub][r];
            v += __shfl_xor(v, 1, 16);
            v += __shfl_xor(v, 2, 16);
            v += __shfl_xor(v, 4, 16);
            v += __shfl_xor(v, 8, 16);
            if (l15 == 0) zpart[wv][sub * 16 + quad * 4 + r] = v;
        }
    __syncthreads();
    if (tid < 64) {
        int rrt = tid >> 5, idx = tid & 31;
        zbuf[(size_t)ch * NTOT + r0 + tid] = zpart[rrt][idx] + zpart[rrt + 2][idx];
    }
}

// ---------------- Stage 1 legacy (fp32 VALU) — ws_size fallback -----------
#define TN2 16
__global__ __launch_bounds__(256) void k_fil(
    const float* __restrict__ x, const float* __restrict__ w1,
    const float* __restrict__ b1, const float* __restrict__ w2,
    float* __restrict__ zout)
{
    __shared__ float xs[TN2][DF];
    __shared__ float part[256];
    const int tid = threadIdx.x;
    const int n0 = blockIdx.x * TN2;
    for (int c = tid; c < TN2 * DF / 4; c += 256) {
        int n = c >> 7, k4 = (c & 127) << 2;
        *(float4*)&xs[n][k4] = *(const float4*)(x + (size_t)(n0 + n) * DF + k4);
    }
    __syncthreads();
    float h[TN2][4];
#pragma unroll
    for (int n = 0; n < TN2; ++n)
#pragma unroll
        for (int q = 0; q < 4; ++q) h[n][q] = 0.f;
    for (int k = 0; k < DF; ++k) {
        float wr[4];
#pragma unroll
        for (int q = 0; q < 4; ++q) wr[q] = w1[(size_t)k * HF + tid + 256 * q];
#pragma unroll
        for (int n = 0; n < TN2; ++n) {
            float xv = xs[n][k];
#pragma unroll
            for (int q = 0; q < 4; ++q) h[n][q] = fmaf(xv, wr[q], h[n][q]);
        }
    }
    float b1r[4], w2r[4];
#pragma unroll
    for (int q = 0; q < 4; ++q) { b1r[q] = b1[tid + 256 * q]; w2r[q] = w2[tid + 256 * q]; }
    for (int n = 0; n < TN2; ++n) {
        float s = 0.f;
#pragma unroll
        for (int q = 0; q < 4; ++q) {
            float hv = h[n][q] + b1r[q];
            s += (hv > 0.f ? hv : 0.f) * w2r[q];
        }
        part[tid] = s;
        __syncthreads();
        for (int off = 128; off > 0; off >>= 1) {
            if (tid < off) part[tid] += part[tid + off];
            __syncthreads();
        }
        if (tid == 0) zout[n0 + n] = part[0];
        __syncthreads();
    }
}

// -- Stage 2 (v18): v16 + replay instruction trim ---------------------------
// Changes vs v16 (45.2us):
//  * replay: `a != b` guard removed — Boruvka min-edge hooks with unique
//    keys form only 2-cycles, so flagged edges are a forest: every replayed
//    edge (within exact lim) merges. Deaths via ONE branch-free ds_write
//    (lane 0 -> dr[young], lanes 1-63 -> dummy slots 256+ln), replacing the
//    dpack mask/shift/cndmask cluster (~6 instr/edge). par/rpack-unpack
//    dropped: epilogue groups components by Boruvka's comp[] (same
//    partition as replay roots).
//  * counting loops vectorized (ulonglong2 / uint4 LDS reads).
__global__ __launch_bounds__(512) void k_pers(
    const int* __restrict__ edges, const float* __restrict__ zbuf,
    const float* __restrict__ b2, float* __restrict__ dout /* [2][NTOT] */)
{
    const int bid = blockIdx.x;
    const int g = bid >> 1, sgn = bid & 1;
    const int tid = threadIdx.x;        // 0..511
    const int v = tid & 255, vh = tid >> 8;

    __shared__ float fv[NODES];
    __shared__ __align__(16) unsigned long long vkey[NODES];
    __shared__ int order_[NODES], rank_[NODES];
    __shared__ float fvr[NODES];
    __shared__ unsigned eks[EDGES];
    __shared__ int comp[NODES];
    __shared__ unsigned minE[NODES];
    __shared__ int nxt[NODES], par2[NODES];
    __shared__ unsigned char mstflag[EDGES];
    __shared__ int cnt, chg;
    __shared__ __align__(16) unsigned mstK[NODES];
    __shared__ unsigned srt[NODES];
    __shared__ int dr[NODES + 64];      // +64 dummy slots for branch-free write
    __shared__ int cmaxr[NODES];
    __shared__ int rkp[512];

    if (tid < 256) {
        float z0 = zbuf[g * NODES + tid] + zbuf[NTOT + g * NODES + tid];
        float f0 = 1.f / (1.f + expf(-(z0 + b2[0])));
        fv[tid] = sgn ? -f0 : f0;
        vkey[tid] = ((unsigned long long)encf(fv[tid]) << 32) | (unsigned)tid;
        srt[tid] = INF32; dr[tid] = 0; cmaxr[tid] = 0;
        comp[tid] = tid;
    }
    __syncthreads();

    // split counting rank (vectorized): (v, vh) counts keys in 128-range
    {
        const unsigned long long mk = vkey[v];
        const int j0 = vh << 7;
        int c = 0;
#pragma unroll 8
        for (int j = j0; j < j0 + 128; j += 2) {
            ulonglong2 kk = *(const ulonglong2*)&vkey[j];
            c += (kk.x < mk) ? 1 : 0;
            c += (kk.y < mk) ? 1 : 0;
        }
        rkp[tid] = c;
    }
    __syncthreads();
    if (tid < 256) {
        int rk = rkp[tid] + rkp[tid + 256];
        order_[rk] = tid;
        rank_[tid] = rk;
        fvr[rk] = fv[tid];
    }
    __syncthreads();

    // edge keys in rank domain; self-loops -> INF (2 edges/thread)
#pragma unroll
    for (int q = 0; q < 2; ++q) {
        int e = tid + q * 512;
        int u = edges[2 * (g * EDGES + e)]     - g * NODES;
        int w = edges[2 * (g * EDGES + e) + 1] - g * NODES;
        if (u == w) { eks[e] = INF32; }
        else {
            int ra = rank_[u], rb = rank_[w];
            int rlo = ra < rb ? ra : rb, rhi = ra < rb ? rb : ra;
            eks[e] = ((unsigned)rhi << 18) | ((unsigned)e << 8) | (unsigned)rlo;
        }
        mstflag[e] = 0;
    }
    __syncthreads();

    // Boruvka with early exit, intra-comp pruning, convergence jumping
    for (int round = 0; round < 8; ++round) {
        if (tid < 256) minE[tid] = INF32;
        if (tid == 0) chg = 0;
        __syncthreads();
#pragma unroll
        for (int q = 0; q < 2; ++q) {
            int e = tid + q * 512;
            unsigned k = eks[e];
            if (k != INF32) {
                int rlo = (int)(k & 255u), rhi = (int)(k >> 18);
                int cu = comp[rlo], cv = comp[rhi];
                if (cu != cv) {
                    atomicMin(&minE[cu], k);
                    atomicMin(&minE[cv], k);
                } else if (!mstflag[e]) {
                    eks[e] = INF32;   // prune: never merges again
                }
            }
        }
        __syncthreads();
        if (tid < 256) {
            unsigned mk = minE[tid];
            int o = tid;
            if (mk != INF32) {
                int rlo = (int)(mk & 255u), rhi = (int)(mk >> 18);
                int cu = comp[rlo], cv = comp[rhi];
                o = (cu == tid) ? cv : cu;
                mstflag[(mk >> 8) & 0x3FFu] = 1;
                chg = 1;
            }
            nxt[tid] = o;
        }
        __syncthreads();
        if (!chg) break;
        if (tid < 256) {
            int o = nxt[tid];
            int p = o;
            if (nxt[o] == tid && tid < o) p = tid;
            par2[tid] = p;
        }
        __syncthreads();
        for (;;) {
            int p = par2[par2[v]];              // duplicated on both halves
            int done = __syncthreads_and(p == par2[v]);
            if (done) break;
            par2[v] = p;                        // benign same-value race
            __syncthreads();
        }
        if (tid < 256) comp[tid] = par2[comp[tid]];
        __syncthreads();
        // connected early-exit: single component => no merges remain
        if (__syncthreads_and(comp[v] == comp[0])) break;
    }

    // collect MST edges (<=255)
    if (tid == 0) cnt = 0;
    __syncthreads();
#pragma unroll
    for (int q = 0; q < 2; ++q) {
        int e = tid + q * 512;
        if (mstflag[e]) {
            int p = atomicAdd(&cnt, 1);
            mstK[p] = eks[e];
        }
    }
    __syncthreads();
    if (tid < 256 && tid >= cnt) mstK[tid] = INF32;
    __syncthreads();

    // split counting sort of MST keys (vectorized)
    {
        const unsigned m2 = mstK[v];
        const int j0 = vh << 7;
        int c = 0;
        if (m2 != INF32) {
#pragma unroll 8
            for (int j = j0; j < j0 + 128; j += 4) {
                uint4 kk = *(const uint4*)&mstK[j];
                c += (kk.x < m2) ? 1 : 0;
                c += (kk.y < m2) ? 1 : 0;
                c += (kk.z < m2) ? 1 : 0;
                c += (kk.w < m2) ? 1 : 0;
            }
        }
        rkp[tid] = c;
    }
    __syncthreads();
    if (tid < 256) {
        unsigned m2 = mstK[tid];
        if (m2 != INF32) srt[rkp[tid] + rkp[tid + 256]] = m2;
    }
    __syncthreads();

    // SWAR replay on wave 0 — deaths only (every edge merges; see header)
    if (tid < 64) {
        const int ln = tid;
        unsigned rpack = (unsigned)ln * 0x01010101u + 0xC0804000u;
        int sv0 = (int)srt[ln], sv1 = (int)srt[ln + 64];
        int sv2 = (int)srt[ln + 128], sv3 = (int)srt[ln + 192];
        const int n = cnt;
        for (int blk = 0; blk < 4; ++blk) {
            const int base = blk << 6;
            if (base >= n) break;
            int lim = n - base; if (lim > 64) lim = 64;
            const int svb = blk == 0 ? sv0 : blk == 1 ? sv1 : blk == 2 ? sv2 : sv3;
            for (int sl = 0; sl < lim; ++sl) {
                const unsigned k = (unsigned)__builtin_amdgcn_readlane(svb, sl);
                const int lo = (int)(k & 255u);
                const int hi = (int)((k >> 18) & 255u);
                const unsigned va = (unsigned)__builtin_amdgcn_readlane((int)rpack, lo & 63);
                const int ca = (int)((va >> ((lo >> 6) << 3)) & 255u);
                const unsigned vb = (unsigned)__builtin_amdgcn_readlane((int)rpack, hi & 63);
                const int cb = (int)((vb >> ((hi >> 6) << 3)) & 255u);
                const int elder = ca < cb ? ca : cb;
                const int young = ca > cb ? ca : cb;
                // SWAR: replace bytes == young with elder (exact zero-detect)
                const unsigned y4 = (unsigned)young * 0x01010101u;
                const unsigned d4 = (unsigned)(young ^ elder) * 0x01010101u;
                const unsigned mm = rpack ^ y4;
                const unsigned ww = (mm | 0x80808080u) - 0x01010101u;
                const unsigned zm = ~(ww | mm) & 0x80808080u;
                rpack ^= d4 & ((zm >> 7) * 255u);
                // death: lane 0 writes dr[young]=hi, others hit dummy slots
                dr[(ln == 0) ? young : (NODES + ln)] = hi;
            }
        }
    }
    __syncthreads();

    // component max (extended persistence); comp[] = same partition as roots
    if (tid < 256) {
        atomicMax(&cmaxr[comp[tid]], tid);
    }
    __syncthreads();

    if (tid < 256) {
        const int db = dr[tid];
        float dv = (db != 0) ? fvr[db] : fvr[cmaxr[comp[tid]]];
        dout[sgn * NTOT + g * NODES + order_[tid]] = dv;
    }
}

// ------- Stage 3: per-pair MLPs + segment sum + linear head (fused) -------
__global__ __launch_bounds__(256) void k_head(
    const float* __restrict__ zbuf, const float* __restrict__ b2,
    const float* __restrict__ dbuf,
    const float* __restrict__ wp0, const float* __restrict__ bp0,
    const float* __restrict__ wp1, const float* __restrict__ bp1,
    const float* __restrict__ wh, const float* __restrict__ bh,
    float* __restrict__ out)
{
    const int g = blockIdx.x, tid = threadIdx.x;
    const int lane = tid & 63, wv = tid >> 6;
    __shared__ float lf[NODES], l0[NODES], l1[NODES];
    __shared__ float wpart[4][NC];
    {
        float z0 = zbuf[g * NODES + tid] + zbuf[NTOT + g * NODES + tid];
        lf[tid] = 1.f / (1.f + expf(-(z0 + b2[0])));
    }
    l0[tid] = dbuf[g * NODES + tid];
    l1[tid] = dbuf[NTOT + g * NODES + tid];
    __syncthreads();
    const float w00 = wp0[tid], w01 = wp0[HP + tid], bb0 = bp0[tid];
    const float w10 = wp1[tid], w11 = wp1[HP + tid], bb1 = bp1[tid];
    float s0 = 0.f, s1 = 0.f;
    for (int n = 0; n < NODES; ++n) {
        float f = lf[n], d0 = l0[n], d1 = l1[n];
        float a0 = fmaf(f, w00, fmaf(d0, w01, bb0));      // h0 = (f, d_sub)
        float a1 = fmaf(-d1, w10, fmaf(f, w11, bb1));     // h1 = (-d_sup, f)
        s0 += a0 > 0.f ? a0 : 0.f;
        s1 += a1 > 0.f ? a1 : 0.f;
    }
    // parallel head: thread tid holds pooled phi0[tid], phi1[tid]
    float pc[NC];
    const float* whr0 = wh + (size_t)tid * NC;
    const float* whr1 = wh + (size_t)(HP + tid) * NC;
#pragma unroll
    for (int c = 0; c < NC; ++c) pc[c] = s0 * whr0[c] + s1 * whr1[c];
#pragma unroll
    for (int off = 32; off > 0; off >>= 1)
#pragma unroll
        for (int c = 0; c < NC; ++c) pc[c] += __shfl_xor(pc[c], off, 64);
    if (lane == 0)
#pragma unroll
        for (int c = 0; c < NC; ++c) wpart[wv][c] = pc[c];
    __syncthreads();
    if (tid < NC)
        out[g * NC + tid] = bh[tid] + wpart[0][tid] + wpart[1][tid]
                          + wpart[2][tid] + wpart[3][tid];
}

extern "C" void kernel_launch(void* const* d_in, const int* in_sizes, int n_in,
                              void* d_out, int out_size, void* d_ws, size_t ws_size,
                              hipStream_t stream)
{
    const float* x   = (const float*)d_in[0];
    const int*   edg = (const int*)d_in[1];
    const float* w1  = (const float*)d_in[3];
    const float* b1  = (const float*)d_in[4];
    const float* w2  = (const float*)d_in[5];
    const float* b2  = (const float*)d_in[6];
    const float* wp0 = (const float*)d_in[7];
    const float* bp0 = (const float*)d_in[8];
    const float* wp1 = (const float*)d_in[9];
    const float* bp1 = (const float*)d_in[10];
    const float* wh  = (const float*)d_in[11];
    const float* bh  = (const float*)d_in[12];

    float* zbuf = (float*)d_ws;                       // [2][NTOT] f32 partials
    float* dbuf = zbuf + 2 * NTOT;                    // [2][NTOT] f32
    unsigned short* w1f = (unsigned short*)(dbuf + 2 * NTOT);  // 1 MB bf16

    const size_t WS_REQ = (size_t)4 * NTOT * 4 + (size_t)HF * DF * 2 + 256;

    if (ws_size >= WS_REQ) {
        k_cvt_frag<<<256, 256, 0, stream>>>(w1, w1f);
        k_fil_mfma<<<512, 256, 0, stream>>>(x, w1f, b1, w2, zbuf);
    } else {
        // fallback: plane 0 from k_fil, plane 1 zeroed
        hipMemsetAsync(zbuf + NTOT, 0, (size_t)NTOT * 4, stream);
        k_fil     <<<NTOT / TN2, 256, 0, stream>>>(x, w1, b1, w2, zbuf);
    }
    k_pers<<<NUM_GRAPHS * 2, 512, 0, stream>>>(edg, zbuf, b2, dbuf);
    k_head<<<NUM_GRAPHS, 256, 0, stream>>>(zbuf, b2, dbuf, wp0, bp0, wp1, bp1,
                                           wh, bh, (float*)d_out);
}